// Round 1
// baseline (260.691 us; speedup 1.0000x reference)
//
#include <hip/hip_runtime.h>
#include <math.h>

// Problem constants (match reference)
constexpr int N = 4096;
constexpr int D = 256;

// ---------------- init: zero deg[N], y1[ND], prop[ND] ----------------
__global__ void k_init(unsigned int* __restrict__ wsu, int ND2) {
    int tid = blockIdx.x * blockDim.x + threadIdx.x;
    int stride = gridDim.x * blockDim.x;
    if (tid < N) wsu[tid] = 0u;                       // deg
    const int base1 = 2 * N;                          // y1 + prop
    for (int j = tid; j < ND2; j += stride) wsu[base1 + j] = 0u;
}

// ---------------- degree over edge entries ----------------
__global__ void k_deg(const int* __restrict__ row, int nnz_e, int* __restrict__ deg) {
    int e = blockIdx.x * blockDim.x + threadIdx.x;
    if (e < nnz_e) atomicAdd(&deg[row[e]], 1);
}

__global__ void k_dis(const int* __restrict__ deg, float* __restrict__ dis) {
    int i = blockIdx.x * blockDim.x + threadIdx.x;
    if (i < N) dis[i] = rsqrtf((float)deg[i] + 1.0f); // +1 = self loop
}

// ---------------- SpMM: Y += S * X over COO (edges + implicit self loops) ----------------
// 64 lanes per entry, 4 floats per lane (float4 load, scalar atomic adds)
__global__ void k_spmm(const int* __restrict__ row, const int* __restrict__ col,
                       int nnz_e, const float* __restrict__ dis,
                       const float* __restrict__ X, float* __restrict__ Y) {
    int e = blockIdx.x * (blockDim.x >> 6) + (threadIdx.x >> 6);
    int lane = threadIdx.x & 63;
    int total = nnz_e + N;
    if (e >= total) return;
    int r, c;
    if (e < nnz_e) { r = row[e]; c = col[e]; }
    else           { r = e - nnz_e; c = r; }
    float w = dis[r] * dis[c];
    const float4 x = *reinterpret_cast<const float4*>(&X[(size_t)c * D + lane * 4]);
    float* yp = &Y[(size_t)r * D + lane * 4];
    atomicAdd(yp + 0, w * x.x);
    atomicAdd(yp + 1, w * x.y);
    atomicAdd(yp + 2, w * x.z);
    atomicAdd(yp + 3, w * x.w);
}

// ---------------- fill agg with -inf ----------------
__global__ void k_fillneg(unsigned int* __restrict__ agg_u, int ND) {
    int tid = blockIdx.x * blockDim.x + threadIdx.x;
    int stride = gridDim.x * blockDim.x;
    for (int j = tid; j < ND; j += stride) agg_u[j] = 0xFF800000u;  // -inf
}

// ---------------- community segment boundaries (comm_ids is sorted) ----------------
__global__ void k_bounds(const int* __restrict__ comm_ids, int M, int C, int* __restrict__ start) {
    int m = blockIdx.x * blockDim.x + threadIdx.x;
    if (m >= M) return;
    int c = comm_ids[m];
    if (m == 0) {
        start[c] = 0;      // c == 0 by construction
        start[C] = M;
    } else if (comm_ids[m - 1] != c) {
        start[c] = m;
    }
}

// float atomic max via sign-split int/uint atomics (handles negatives and -0.0)
__device__ inline void atomicMaxFloat(float* addr, float val) {
    unsigned int u = __float_as_uint(val);
    if (u < 0x80000000u) atomicMax((int*)addr, (int)u);              // val >= +0.0
    else                 atomicMin((unsigned int*)addr, u);          // val <= -0.0
}

// ---------------- per-community mean + atomic max into owner row ----------------
__global__ void k_comm(const int* __restrict__ member_nodes, const int* __restrict__ start,
                       const int* __restrict__ comm_owner,
                       const float* __restrict__ prop, float* __restrict__ agg) {
    int c = blockIdx.x;
    int d = threadIdx.x;              // blockDim.x == D == 256
    int s = start[c], e = start[c + 1];
    float sum = 0.0f;
    for (int m = s; m < e; ++m) {
        int node = member_nodes[m];
        sum += prop[(size_t)node * D + d];
    }
    float mean = sum / (float)(e - s);
    int owner = comm_owner[c];
    atomicMaxFloat(&agg[(size_t)owner * D + d], mean);
}

// ---------------- final: out[:, :D] = relu(prop); out[:, D:] = relu(has ? agg : prop) ----------------
__global__ void k_final(const float* __restrict__ prop, const float* __restrict__ agg,
                        float* __restrict__ out) {
    int i = blockIdx.x * blockDim.x + threadIdx.x;   // over N*D
    int v = i >> 8;                                   // D == 256
    int d = i & (D - 1);
    float p = prop[i];
    float a = agg[i];
    float second = (a == -INFINITY) ? p : a;
    out[(size_t)v * (2 * D) + d] = fmaxf(p, 0.0f);
    out[(size_t)v * (2 * D) + D + d] = fmaxf(second, 0.0f);
}

extern "C" void kernel_launch(void* const* d_in, const int* in_sizes, int n_in,
                              void* d_out, int out_size, void* d_ws, size_t ws_size,
                              hipStream_t stream) {
    const int*   edge_index   = (const int*)d_in[0];
    const float* X            = (const float*)d_in[1];
    const int*   member_nodes = (const int*)d_in[2];
    const int*   comm_ids     = (const int*)d_in[3];
    const int*   comm_owner   = (const int*)d_in[4];

    const int nnz_e = in_sizes[0] / 2;   // 24576 directed edge entries
    const int M     = in_sizes[2];       // total membership entries
    const int C     = in_sizes[4];       // number of communities

    // workspace layout (4-byte elements):
    //   [0, N)            deg (int)
    //   [N, 2N)           dis (float)
    //   [2N, 2N+ND)       y1 (float)       -- later reused as agg
    //   [2N+ND, 2N+2ND)   prop (float)
    //   [2N+2ND, ...)     start (int, C+1)
    const int ND = N * D;
    unsigned int* wsu = (unsigned int*)d_ws;
    int*   deg   = (int*)d_ws;
    float* dis   = (float*)d_ws + N;
    float* y1    = (float*)d_ws + 2 * N;
    float* prop  = y1 + ND;
    int*   start = (int*)(prop + ND);
    float* agg   = y1;   // alias: y1 dead after SpMM2

    k_init<<<2048, 256, 0, stream>>>(wsu, 2 * ND);
    k_deg<<<(nnz_e + 255) / 256, 256, 0, stream>>>(edge_index, nnz_e, deg);
    k_dis<<<(N + 255) / 256, 256, 0, stream>>>(deg, dis);

    const int nnz_total = nnz_e + N;
    const int entries_per_block = 4;   // 256 threads / 64 lanes
    const int spmm_grid = (nnz_total + entries_per_block - 1) / entries_per_block;
    const int* row = edge_index;
    const int* col = edge_index + nnz_e;
    k_spmm<<<spmm_grid, 256, 0, stream>>>(row, col, nnz_e, dis, X, y1);     // y1 = S @ X
    k_spmm<<<spmm_grid, 256, 0, stream>>>(row, col, nnz_e, dis, y1, prop);  // prop = S @ y1
    // NOTE: prop must be read before overwriting y1/agg... but k_spmm #2 only READS y1
    // and WRITES prop; after it completes, y1 is dead and becomes agg.
    k_fillneg<<<1024, 256, 0, stream>>>((unsigned int*)agg, ND);

    k_bounds<<<(M + 255) / 256, 256, 0, stream>>>(comm_ids, M, C, start);
    k_comm<<<C, D, 0, stream>>>(member_nodes, start, comm_owner, prop, agg);
    k_final<<<ND / 256, 256, 0, stream>>>(prop, agg, (float*)d_out);
}

// Round 2
// 82.543 us; speedup vs baseline: 3.1582x; 3.1582x over previous
//
#include <hip/hip_runtime.h>
#include <math.h>

constexpr int N = 4096;
constexpr int D = 256;

// ---------------- zero deg ----------------
__global__ void k_zero(int* __restrict__ deg) {
    int i = blockIdx.x * blockDim.x + threadIdx.x;
    if (i < N) deg[i] = 0;
}

// ---------------- degree over directed edge entries ----------------
__global__ void k_deg(const int* __restrict__ row, int nnz_e, int* __restrict__ deg) {
    int e = blockIdx.x * blockDim.x + threadIdx.x;
    if (e < nnz_e) atomicAdd(&deg[row[e]], 1);
}

// ---------------- single-block scan: rowptr/cursor from deg, plus dis ----------------
// 256 threads x 16 elements each covers N=4096.
__global__ void k_scan(const int* __restrict__ deg, int* __restrict__ rowptr,
                       int* __restrict__ cursor, float* __restrict__ dis) {
    __shared__ int part[256];
    int t = threadIdx.x;
    int base = t * 16;
    int local[16];
    int s = 0;
    for (int i = 0; i < 16; ++i) {
        local[i] = s;
        s += deg[base + i];
    }
    part[t] = s;
    __syncthreads();
    for (int off = 1; off < 256; off <<= 1) {
        int v = (t >= off) ? part[t - off] : 0;
        __syncthreads();
        part[t] += v;
        __syncthreads();
    }
    int prefix = (t == 0) ? 0 : part[t - 1];
    for (int i = 0; i < 16; ++i) {
        int rp = prefix + local[i];
        rowptr[base + i] = rp;
        cursor[base + i] = rp;
        dis[base + i] = rsqrtf((float)deg[base + i] + 1.0f);  // +1 = self loop
    }
    if (t == 255) rowptr[N] = part[255];
}

__device__ inline int lower_bound(const int* __restrict__ a, int n, int key) {
    int lo = 0, hi = n;
    while (lo < hi) {
        int mid = (lo + hi) >> 1;
        if (a[mid] < key) lo = mid + 1; else hi = mid;
    }
    return lo;
}

// ---------------- scatter edges into CSR + segment boundaries via binary search ----------------
__global__ void k_scatter_bounds(const int* __restrict__ row, const int* __restrict__ col,
                                 int nnz_e, const float* __restrict__ dis,
                                 int* __restrict__ cursor,
                                 int* __restrict__ csr_col, float* __restrict__ csr_w,
                                 const int* __restrict__ comm_ids, int M, int C,
                                 int* __restrict__ start,
                                 const int* __restrict__ comm_owner, int* __restrict__ ostart) {
    int t = blockIdx.x * blockDim.x + threadIdx.x;
    if (t < nnz_e) {
        int r = row[t], c = col[t];
        int pos = atomicAdd(&cursor[r], 1);
        csr_col[pos] = c;
        csr_w[pos] = dis[r] * dis[c];
    }
    if (t <= C) start[t] = lower_bound(comm_ids, M, t);
    if (t <= N) ostart[t] = lower_bound(comm_owner, C, t);
}

// ---------------- CSR SpMM (gather): one wave per row, 4 floats per lane ----------------
__global__ void k_spmm(const int* __restrict__ rowptr, const int* __restrict__ csr_col,
                       const float* __restrict__ csr_w, const float* __restrict__ dis,
                       const float* __restrict__ X, float* __restrict__ Y) {
    int r = blockIdx.x * (blockDim.x >> 6) + (threadIdx.x >> 6);
    int lane = threadIdx.x & 63;
    if (r >= N) return;
    int s = rowptr[r], e = rowptr[r + 1];
    float dr = dis[r];
    const float4 xs = *reinterpret_cast<const float4*>(&X[(size_t)r * D + lane * 4]);
    float w0 = dr * dr;  // implicit self loop
    float4 acc;
    acc.x = w0 * xs.x; acc.y = w0 * xs.y; acc.z = w0 * xs.z; acc.w = w0 * xs.w;
    for (int j = s; j < e; ++j) {
        int c = csr_col[j];
        float w = csr_w[j];
        const float4 x = *reinterpret_cast<const float4*>(&X[(size_t)c * D + lane * 4]);
        acc.x += w * x.x; acc.y += w * x.y; acc.z += w * x.z; acc.w += w * x.w;
    }
    *reinterpret_cast<float4*>(&Y[(size_t)r * D + lane * 4]) = acc;
}

// ---------------- fused community mean + owner max + fallback + relu + concat ----------------
// One block per owner node v; 256 threads = feature dim.
__global__ void k_owner(const int* __restrict__ member_nodes, const int* __restrict__ start,
                        const int* __restrict__ ostart,
                        const float* __restrict__ prop, float* __restrict__ out) {
    int v = blockIdx.x;
    int d = threadIdx.x;
    float p = prop[(size_t)v * D + d];
    int cs = ostart[v], ce = ostart[v + 1];
    float second;
    if (cs == ce) {
        second = p;  // fallback: no community
    } else {
        float mx = -INFINITY;
        for (int c = cs; c < ce; ++c) {
            int ms = start[c], me = start[c + 1];
            float sum = 0.0f;
            for (int m = ms; m < me; ++m) {
                sum += prop[(size_t)member_nodes[m] * D + d];
            }
            mx = fmaxf(mx, sum / (float)(me - ms));
        }
        second = mx;
    }
    out[(size_t)v * (2 * D) + d] = fmaxf(p, 0.0f);
    out[(size_t)v * (2 * D) + D + d] = fmaxf(second, 0.0f);
}

extern "C" void kernel_launch(void* const* d_in, const int* in_sizes, int n_in,
                              void* d_out, int out_size, void* d_ws, size_t ws_size,
                              hipStream_t stream) {
    const int*   edge_index   = (const int*)d_in[0];
    const float* X            = (const float*)d_in[1];
    const int*   member_nodes = (const int*)d_in[2];
    const int*   comm_ids     = (const int*)d_in[3];
    const int*   comm_owner   = (const int*)d_in[4];

    const int nnz_e = in_sizes[0] / 2;   // directed edge entries (24576)
    const int M     = in_sizes[2];       // total membership entries
    const int C     = in_sizes[4];       // number of communities

    const int ND = N * D;
    int* ws = (int*)d_ws;
    int off = 0;
    int*   deg     = ws + off; off += N;
    float* dis     = (float*)(ws + off); off += N;
    int*   rowptr  = ws + off; off += N + 1;
    int*   cursor  = ws + off; off += N;
    int*   csr_col = ws + off; off += nnz_e;
    float* csr_w   = (float*)(ws + off); off += nnz_e;
    off = (off + 3) & ~3;                 // 16B align for float4
    float* y1      = (float*)(ws + off); off += ND;
    float* prop    = (float*)(ws + off); off += ND;
    int*   start   = ws + off; off += C + 1;
    int*   ostart  = ws + off; off += N + 1;

    const int* row = edge_index;
    const int* col = edge_index + nnz_e;

    k_zero<<<(N + 255) / 256, 256, 0, stream>>>(deg);
    k_deg<<<(nnz_e + 255) / 256, 256, 0, stream>>>(row, nnz_e, deg);
    k_scan<<<1, 256, 0, stream>>>(deg, rowptr, cursor, dis);

    int maxt = nnz_e;
    if (C + 1 > maxt) maxt = C + 1;
    if (N + 1 > maxt) maxt = N + 1;
    k_scatter_bounds<<<(maxt + 255) / 256, 256, 0, stream>>>(
        row, col, nnz_e, dis, cursor, csr_col, csr_w,
        comm_ids, M, C, start, comm_owner, ostart);

    k_spmm<<<(N + 3) / 4, 256, 0, stream>>>(rowptr, csr_col, csr_w, dis, X, y1);
    k_spmm<<<(N + 3) / 4, 256, 0, stream>>>(rowptr, csr_col, csr_w, dis, y1, prop);

    k_owner<<<N, D, 0, stream>>>(member_nodes, start, ostart, prop, (float*)d_out);
}